// Round 1
// baseline (141.637 us; speedup 1.0000x reference)
//
#include <hip/hip_runtime.h>

#define NCLS 345
#define CPAD 384
#define DIM  512
#define MAXS 512
#define BM   64
#define BK   64

typedef float f32x4 __attribute__((ext_vector_type(4)));
typedef short s16x8 __attribute__((ext_vector_type(8)));

__device__ __forceinline__ short f2bf(float f) {
  union { float f; unsigned u; } v; v.f = f;
  unsigned r = v.u + 0x7fffu + ((v.u >> 16) & 1u);   // round-to-nearest-even
  return (short)(r >> 16);
}

// ---- Kernel A: per-class stable top-K selection + weight column build ----
// One block per (padded) class. Emits bf16 W^T [CPAD][DIM] into workspace,
// zero rows for c >= NCLS.
__global__ __launch_bounds__(256) void build_weights(
    const float* __restrict__ supports, const float* __restrict__ ent,
    const int* __restrict__ y_hat, const int* __restrict__ fKp,
    short* __restrict__ Wt, int N)
{
  const int c = blockIdx.x;
  const int tid = threadIdx.x;
  if (c >= NCLS) {
    for (int d = tid; d < DIM; d += 256) Wt[(size_t)c * DIM + d] = 0;
    return;
  }
  __shared__ float s_ent[MAXS];
  __shared__ int   s_idx[MAXS];
  __shared__ int   s_sel[MAXS];
  __shared__ int   s_cnt;
  __shared__ float s_part[4][DIM];
  __shared__ float s_red[4];
  if (tid == 0) s_cnt = 0;
  __syncthreads();
  // gather this class's (ent, idx) list
  for (int i = tid; i < N; i += 256) {
    if (y_hat[i] == c) {
      int p = atomicAdd(&s_cnt, 1);
      if (p < MAXS) { s_ent[p] = ent[i]; s_idx[p] = i; }
    }
  }
  __syncthreads();
  const int S = min(s_cnt, MAXS);
  const int K = fKp[0];
  // stable rank within class: count elements strictly before in (ent, idx) order
  for (int e = tid; e < S; e += 256) {
    float ee = s_ent[e]; int ie = s_idx[e];
    int cnt = 0;
    for (int j = 0; j < S; ++j) {
      float ej = s_ent[j];
      cnt += ((ej < ee) || (ej == ee && s_idx[j] < ie)) ? 1 : 0;
    }
    s_sel[e] = (cnt < K) ? 1 : 0;
  }
  __syncthreads();
  // accumulate normalized selected rows; wave w takes e = w, w+4, ...
  const int lane = tid & 63, w = tid >> 6;
  float part[8];
#pragma unroll
  for (int j = 0; j < 8; ++j) part[j] = 0.f;
  for (int e = w; e < S; e += 4) {
    if (!s_sel[e]) continue;                       // wave-uniform branch
    const float* row = supports + (size_t)s_idx[e] * DIM;
    float v[8], ss = 0.f;
#pragma unroll
    for (int j = 0; j < 8; ++j) { v[j] = row[lane + 64 * j]; ss += v[j] * v[j]; }
#pragma unroll
    for (int off = 32; off; off >>= 1) ss += __shfl_xor(ss, off);
    float sc = 1.f / fmaxf(sqrtf(ss), 1e-12f);
#pragma unroll
    for (int j = 0; j < 8; ++j) part[j] += v[j] * sc;
  }
#pragma unroll
  for (int j = 0; j < 8; ++j) s_part[w][lane + 64 * j] = part[j];
  __syncthreads();
  // combine 4 wave-partials, column-normalize, emit bf16
  float w0 = s_part[0][tid] + s_part[1][tid] + s_part[2][tid] + s_part[3][tid];
  float w1 = s_part[0][tid + 256] + s_part[1][tid + 256] + s_part[2][tid + 256] + s_part[3][tid + 256];
  float loc = w0 * w0 + w1 * w1;
#pragma unroll
  for (int off = 32; off; off >>= 1) loc += __shfl_xor(loc, off);
  if (lane == 0) s_red[w] = loc;
  __syncthreads();
  float tot = s_red[0] + s_red[1] + s_red[2] + s_red[3];
  float sc = 1.f / fmaxf(sqrtf(tot), 1e-12f);
  Wt[(size_t)c * DIM + tid]       = f2bf(w0 * sc);
  Wt[(size_t)c * DIM + tid + 256] = f2bf(w1 * sc);
}

// ---- Kernel B: out[M,345] = z[M,512] @ W  via bf16 MFMA, B^T layout ----
// BM=64 x BN=384 (full padded N -> z read exactly once), BK=64, 8 waves (2Mx4N).
// Per wave: 2 M-tiles x 6 N-tiles of 16x16. LDS tiles XOR-swizzled (row&7)<<4.
__global__ __launch_bounds__(512) void gemm_zw(
    const float* __restrict__ z, const short* __restrict__ Wt,
    float* __restrict__ out)
{
  __shared__ __align__(16) short lA[BM * BK];     // 8 KB
  __shared__ __align__(16) short lB[CPAD * BK];   // 48 KB
  const int tid = threadIdx.x;
  const int bm = blockIdx.x;
  const int rb  = tid >> 3;    // 0..63 staging row
  const int seg = tid & 7;     // 0..7 (8 elems = 16B each)
  const float* gA = z  + (size_t)(bm * BM + rb) * DIM + seg * 8;
  const short* gB = Wt + (size_t)rb * DIM + seg * 8;
  const unsigned wA = (unsigned)(rb * 128 + seg * 16) ^ ((rb & 7) << 4);
  char* const cA = (char*)lA;
  char* const cB = (char*)lB;

  const int lane = tid & 63, wid = tid >> 6;
  const int wm = wid >> 2, wn = wid & 3;
  const int fr = lane & 15, fq = lane >> 4;
  unsigned roA[2], roB[6];
#pragma unroll
  for (int mt = 0; mt < 2; ++mt) {
    int r = wm * 32 + mt * 16 + fr;
    roA[mt] = (unsigned)(r * 128 + fq * 16) ^ ((r & 7) << 4);
  }
#pragma unroll
  for (int nt = 0; nt < 6; ++nt) {
    int r = wn * 96 + nt * 16 + fr;
    roB[nt] = (unsigned)(r * 128 + fq * 16) ^ ((r & 7) << 4);
  }
  f32x4 acc[2][6];
#pragma unroll
  for (int mt = 0; mt < 2; ++mt)
#pragma unroll
    for (int nt = 0; nt < 6; ++nt) acc[mt][nt] = f32x4{0.f, 0.f, 0.f, 0.f};

  for (int kt = 0; kt < DIM / BK; ++kt) {
    // issue global loads first (overlap with other waves' compute)
    const float* pa = gA + kt * BK;
    f32x4 a0 = *(const f32x4*)pa;
    f32x4 a1 = *(const f32x4*)(pa + 4);
    s16x8 b[6];
#pragma unroll
    for (int rep = 0; rep < 6; ++rep)
      b[rep] = *(const s16x8*)(gB + (size_t)rep * 64 * DIM + kt * BK);
    s16x8 a16;
#pragma unroll
    for (int j = 0; j < 4; ++j) { a16[j] = f2bf(a0[j]); a16[4 + j] = f2bf(a1[j]); }
    __syncthreads();                 // previous iter's LDS reads done
    *(s16x8*)(cA + wA) = a16;
#pragma unroll
    for (int rep = 0; rep < 6; ++rep)
      *(s16x8*)(cB + wA + rep * 8192) = b[rep];   // row = rb + rep*64, same swizzle bits
    __syncthreads();                 // staging visible
#pragma unroll
    for (int kk = 0; kk < 2; ++kk) {
      const unsigned kx = (unsigned)(kk << 6);    // +64B raw, bit6 clear in ro* -> XOR ok
      s16x8 af[2], bf[6];
#pragma unroll
      for (int mt = 0; mt < 2; ++mt) af[mt] = *(const s16x8*)(cA + (roA[mt] ^ kx));
#pragma unroll
      for (int nt = 0; nt < 6; ++nt) bf[nt] = *(const s16x8*)(cB + (roB[nt] ^ kx));
#pragma unroll
      for (int mt = 0; mt < 2; ++mt)
#pragma unroll
        for (int nt = 0; nt < 6; ++nt)
          acc[mt][nt] = __builtin_amdgcn_mfma_f32_16x16x32_bf16(af[mt], bf[nt], acc[mt][nt], 0, 0, 0);
    }
  }
  // epilogue: C layout col = lane&15, row = (lane>>4)*4 + j  (m89-verified)
#pragma unroll
  for (int mt = 0; mt < 2; ++mt) {
    int r0 = bm * BM + wm * 32 + mt * 16 + fq * 4;
#pragma unroll
    for (int nt = 0; nt < 6; ++nt) {
      int col = wn * 96 + nt * 16 + fr;
      if (col < NCLS) {
#pragma unroll
        for (int j = 0; j < 4; ++j)
          out[(size_t)(r0 + j) * NCLS + col] = acc[mt][nt][j];
      }
    }
  }
}

extern "C" void kernel_launch(void* const* d_in, const int* in_sizes, int n_in,
                              void* d_out, int out_size, void* d_ws, size_t ws_size,
                              hipStream_t stream) {
  const float* z        = (const float*)d_in[0];
  const float* supports = (const float*)d_in[1];
  const float* ent      = (const float*)d_in[2];
  const int*   y_hat    = (const int*)d_in[3];
  const int*   fK       = (const int*)d_in[4];
  float* out = (float*)d_out;
  short* Wt  = (short*)d_ws;          // CPAD*DIM bf16 = 384 KB scratch
  const int N = in_sizes[2];
  const int M = in_sizes[0] / DIM;    // 65536
  build_weights<<<dim3(CPAD), dim3(256), 0, stream>>>(supports, ent, y_hat, fK, Wt, N);
  gemm_zw<<<dim3(M / BM), dim3(512), 0, stream>>>(z, Wt, out);
}

// Round 2
// 101.695 us; speedup vs baseline: 1.3928x; 1.3928x over previous
//
#include <hip/hip_runtime.h>

#define NCLS 345
#define CPAD 384
#define DIM  512
#define MAXS 512
#define BCAP 256
#define BM   64
#define BK   64

typedef float f32x4 __attribute__((ext_vector_type(4)));
typedef short s16x8 __attribute__((ext_vector_type(8)));
typedef unsigned long long u64;

__device__ __forceinline__ short f2bf(float f) {
  union { float f; unsigned u; } v; v.f = f;
  unsigned r = v.u + 0x7fffu + ((v.u >> 16) & 1u);   // round-to-nearest-even
  return (short)(r >> 16);
}

// ---- Stage 1: one pass over N, bucket (ent_bits<<32)|idx per class ----
// ent in [0,1): positive-float bits are order-monotone, so u64 compare
// reproduces the stable (ent, idx) argsort order exactly.
__global__ __launch_bounds__(256) void scan_classes(
    const float* __restrict__ ent, const int* __restrict__ y_hat,
    u64* __restrict__ bucket, int* __restrict__ cnt, int N)
{
  int i = blockIdx.x * 256 + threadIdx.x;
  if (i >= N) return;
  int c = y_hat[i];
  unsigned eb = __float_as_uint(ent[i]);
  u64 key = ((u64)eb << 32) | (unsigned)i;
  int p = atomicAdd(&cnt[c], 1);
  if (p < BCAP) bucket[(size_t)c * BCAP + p] = key;
}

// ---- Stage 2: per-class select (exact stable rank) + normalized-row sum ----
__global__ __launch_bounds__(512) void select_accum(
    const float* __restrict__ supports, const u64* __restrict__ bucket,
    const int* __restrict__ cnt, const int* __restrict__ fKp,
    short* __restrict__ Wt)
{
  const int c = blockIdx.x;
  const int tid = threadIdx.x;
  const int lane = tid & 63, w = tid >> 6;
  __shared__ u64   s_key[BCAP];
  __shared__ int   s_selidx[BCAP];
  __shared__ int   s_nsel;
  __shared__ float s_part[8][DIM];   // 16 KB
  __shared__ float s_red[8];
  if (tid == 0) s_nsel = 0;
  const int S = (c < NCLS) ? min(cnt[c], BCAP) : 0;
  const int K = fKp[0];
  for (int e = tid; e < S; e += 512) s_key[e] = bucket[(size_t)c * BCAP + e];
  __syncthreads();
  for (int e = tid; e < S; e += 512) {
    u64 ke = s_key[e];
    int r = 0;
    for (int j = 0; j < S; ++j) r += (s_key[j] < ke) ? 1 : 0;
    if (r < K) { int p = atomicAdd(&s_nsel, 1); s_selidx[p] = (int)(unsigned)(ke & 0xffffffffull); }
  }
  __syncthreads();
  const int nsel = s_nsel;
  // 8 waves; 2 rows in flight per wave to overlap the shuffle chains
  f32x4 p0 = {0.f,0.f,0.f,0.f}, p1 = {0.f,0.f,0.f,0.f};
  for (int e0 = w; e0 < nsel; e0 += 16) {
    const int e1 = e0 + 8;
    const bool h1 = (e1 < nsel);                 // wave-uniform
    const f32x4* r0 = (const f32x4*)(supports + (size_t)s_selidx[e0] * DIM);
    f32x4 a0 = r0[lane], a1 = r0[lane + 64];
    f32x4 b0 = {0.f,0.f,0.f,0.f}, b1 = {0.f,0.f,0.f,0.f};
    if (h1) {
      const f32x4* r1 = (const f32x4*)(supports + (size_t)s_selidx[e1] * DIM);
      b0 = r1[lane]; b1 = r1[lane + 64];
    }
    float s0 = 0.f, s1 = 0.f;
#pragma unroll
    for (int j = 0; j < 4; ++j) {
      s0 = fmaf(a0[j], a0[j], s0); s0 = fmaf(a1[j], a1[j], s0);
      s1 = fmaf(b0[j], b0[j], s1); s1 = fmaf(b1[j], b1[j], s1);
    }
#pragma unroll
    for (int off = 32; off; off >>= 1) { s0 += __shfl_xor(s0, off); s1 += __shfl_xor(s1, off); }
    float c0 = 1.f / fmaxf(sqrtf(s0), 1e-12f);
    float c1 = 1.f / fmaxf(sqrtf(s1), 1e-12f);
#pragma unroll
    for (int j = 0; j < 4; ++j) { p0[j] = fmaf(a0[j], c0, p0[j]); p1[j] = fmaf(a1[j], c0, p1[j]); }
    if (h1) {
#pragma unroll
      for (int j = 0; j < 4; ++j) { p0[j] = fmaf(b0[j], c1, p0[j]); p1[j] = fmaf(b1[j], c1, p1[j]); }
    }
  }
  *(f32x4*)&s_part[w][lane * 4]       = p0;
  *(f32x4*)&s_part[w][256 + lane * 4] = p1;
  __syncthreads();
  float acc = 0.f;
#pragma unroll
  for (int ww = 0; ww < 8; ++ww) acc += s_part[ww][tid];
  float sq = acc * acc;
#pragma unroll
  for (int off = 32; off; off >>= 1) sq += __shfl_xor(sq, off);
  if (lane == 0) s_red[w] = sq;
  __syncthreads();
  float tot = 0.f;
#pragma unroll
  for (int ww = 0; ww < 8; ++ww) tot += s_red[ww];
  float sc = 1.f / fmaxf(sqrtf(tot), 1e-12f);
  Wt[(size_t)c * DIM + tid] = f2bf(acc * sc);
}

// ---- Fallback (ws too small): round-1 monolithic builder ----
__global__ __launch_bounds__(256) void build_weights(
    const float* __restrict__ supports, const float* __restrict__ ent,
    const int* __restrict__ y_hat, const int* __restrict__ fKp,
    short* __restrict__ Wt, int N)
{
  const int c = blockIdx.x;
  const int tid = threadIdx.x;
  if (c >= NCLS) {
    for (int d = tid; d < DIM; d += 256) Wt[(size_t)c * DIM + d] = 0;
    return;
  }
  __shared__ float s_ent[MAXS];
  __shared__ int   s_idx[MAXS];
  __shared__ int   s_sel[MAXS];
  __shared__ int   s_cnt;
  __shared__ float s_part[4][DIM];
  __shared__ float s_red[4];
  if (tid == 0) s_cnt = 0;
  __syncthreads();
  for (int i = tid; i < N; i += 256) {
    if (y_hat[i] == c) {
      int p = atomicAdd(&s_cnt, 1);
      if (p < MAXS) { s_ent[p] = ent[i]; s_idx[p] = i; }
    }
  }
  __syncthreads();
  const int S = min(s_cnt, MAXS);
  const int K = fKp[0];
  for (int e = tid; e < S; e += 256) {
    float ee = s_ent[e]; int ie = s_idx[e];
    int cnt2 = 0;
    for (int j = 0; j < S; ++j) {
      float ej = s_ent[j];
      cnt2 += ((ej < ee) || (ej == ee && s_idx[j] < ie)) ? 1 : 0;
    }
    s_sel[e] = (cnt2 < K) ? 1 : 0;
  }
  __syncthreads();
  const int lane = tid & 63, w = tid >> 6;
  float part[8];
#pragma unroll
  for (int j = 0; j < 8; ++j) part[j] = 0.f;
  for (int e = w; e < S; e += 4) {
    if (!s_sel[e]) continue;
    const float* row = supports + (size_t)s_idx[e] * DIM;
    float v[8], ss = 0.f;
#pragma unroll
    for (int j = 0; j < 8; ++j) { v[j] = row[lane + 64 * j]; ss += v[j] * v[j]; }
#pragma unroll
    for (int off = 32; off; off >>= 1) ss += __shfl_xor(ss, off);
    float sc = 1.f / fmaxf(sqrtf(ss), 1e-12f);
#pragma unroll
    for (int j = 0; j < 8; ++j) part[j] += v[j] * sc;
  }
#pragma unroll
  for (int j = 0; j < 8; ++j) s_part[w][lane + 64 * j] = part[j];
  __syncthreads();
  float w0 = s_part[0][tid] + s_part[1][tid] + s_part[2][tid] + s_part[3][tid];
  float w1 = s_part[0][tid + 256] + s_part[1][tid + 256] + s_part[2][tid + 256] + s_part[3][tid + 256];
  float loc = w0 * w0 + w1 * w1;
#pragma unroll
  for (int off = 32; off; off >>= 1) loc += __shfl_xor(loc, off);
  if (lane == 0) s_red[w] = loc;
  __syncthreads();
  float tot = s_red[0] + s_red[1] + s_red[2] + s_red[3];
  float sc = 1.f / fmaxf(sqrtf(tot), 1e-12f);
  Wt[(size_t)c * DIM + tid]       = f2bf(w0 * sc);
  Wt[(size_t)c * DIM + tid + 256] = f2bf(w1 * sc);
}

// ---- Kernel B: out[M,345] = z[M,512] @ W  via bf16 MFMA, B^T layout ----
__global__ __launch_bounds__(512) void gemm_zw(
    const float* __restrict__ z, const short* __restrict__ Wt,
    float* __restrict__ out)
{
  __shared__ __align__(16) short lA[BM * BK];     // 8 KB
  __shared__ __align__(16) short lB[CPAD * BK];   // 48 KB
  const int tid = threadIdx.x;
  const int bm = blockIdx.x;
  const int rb  = tid >> 3;
  const int seg = tid & 7;
  const float* gA = z  + (size_t)(bm * BM + rb) * DIM + seg * 8;
  const short* gB = Wt + (size_t)rb * DIM + seg * 8;
  const unsigned wA = (unsigned)(rb * 128 + seg * 16) ^ ((rb & 7) << 4);
  char* const cA = (char*)lA;
  char* const cB = (char*)lB;

  const int lane = tid & 63, wid = tid >> 6;
  const int wm = wid >> 2, wn = wid & 3;
  const int fr = lane & 15, fq = lane >> 4;
  unsigned roA[2], roB[6];
#pragma unroll
  for (int mt = 0; mt < 2; ++mt) {
    int r = wm * 32 + mt * 16 + fr;
    roA[mt] = (unsigned)(r * 128 + fq * 16) ^ ((r & 7) << 4);
  }
#pragma unroll
  for (int nt = 0; nt < 6; ++nt) {
    int r = wn * 96 + nt * 16 + fr;
    roB[nt] = (unsigned)(r * 128 + fq * 16) ^ ((r & 7) << 4);
  }
  f32x4 acc[2][6];
#pragma unroll
  for (int mt = 0; mt < 2; ++mt)
#pragma unroll
    for (int nt = 0; nt < 6; ++nt) acc[mt][nt] = f32x4{0.f, 0.f, 0.f, 0.f};

  for (int kt = 0; kt < DIM / BK; ++kt) {
    const float* pa = gA + kt * BK;
    f32x4 a0 = *(const f32x4*)pa;
    f32x4 a1 = *(const f32x4*)(pa + 4);
    s16x8 b[6];
#pragma unroll
    for (int rep = 0; rep < 6; ++rep)
      b[rep] = *(const s16x8*)(gB + (size_t)rep * 64 * DIM + kt * BK);
    s16x8 a16;
#pragma unroll
    for (int j = 0; j < 4; ++j) { a16[j] = f2bf(a0[j]); a16[4 + j] = f2bf(a1[j]); }
    __syncthreads();
    *(s16x8*)(cA + wA) = a16;
#pragma unroll
    for (int rep = 0; rep < 6; ++rep)
      *(s16x8*)(cB + wA + rep * 8192) = b[rep];
    __syncthreads();
#pragma unroll
    for (int kk = 0; kk < 2; ++kk) {
      const unsigned kx = (unsigned)(kk << 6);
      s16x8 af[2], bfr[6];
#pragma unroll
      for (int mt = 0; mt < 2; ++mt) af[mt] = *(const s16x8*)(cA + (roA[mt] ^ kx));
#pragma unroll
      for (int nt = 0; nt < 6; ++nt) bfr[nt] = *(const s16x8*)(cB + (roB[nt] ^ kx));
#pragma unroll
      for (int mt = 0; mt < 2; ++mt)
#pragma unroll
        for (int nt = 0; nt < 6; ++nt)
          acc[mt][nt] = __builtin_amdgcn_mfma_f32_16x16x32_bf16(af[mt], bfr[nt], acc[mt][nt], 0, 0, 0);
    }
  }
#pragma unroll
  for (int mt = 0; mt < 2; ++mt) {
    int r0 = bm * BM + wm * 32 + mt * 16 + fq * 4;
#pragma unroll
    for (int nt = 0; nt < 6; ++nt) {
      int col = wn * 96 + nt * 16 + fr;
      if (col < NCLS) {
#pragma unroll
        for (int j = 0; j < 4; ++j)
          out[(size_t)(r0 + j) * NCLS + col] = acc[mt][nt][j];
      }
    }
  }
}

extern "C" void kernel_launch(void* const* d_in, const int* in_sizes, int n_in,
                              void* d_out, int out_size, void* d_ws, size_t ws_size,
                              hipStream_t stream) {
  const float* z        = (const float*)d_in[0];
  const float* supports = (const float*)d_in[1];
  const float* ent      = (const float*)d_in[2];
  const int*   y_hat    = (const int*)d_in[3];
  const int*   fK       = (const int*)d_in[4];
  float* out = (float*)d_out;
  short* Wt  = (short*)d_ws;
  const int N = in_sizes[2];
  const int M = in_sizes[0] / DIM;

  const size_t offC = (size_t)CPAD * DIM * 2;          // 393216
  const size_t offB = offC + 2048;                     // cnt region padded
  const size_t need = offB + (size_t)CPAD * BCAP * 8;  // ~1.13 MB
  if (ws_size >= need) {
    int* cnt    = (int*)((char*)d_ws + offC);
    u64* bucket = (u64*)((char*)d_ws + offB);
    hipMemsetAsync(cnt, 0, CPAD * sizeof(int), stream);
    scan_classes<<<dim3((N + 255) / 256), dim3(256), 0, stream>>>(ent, y_hat, bucket, cnt, N);
    select_accum<<<dim3(CPAD), dim3(512), 0, stream>>>(supports, bucket, cnt, fK, Wt);
  } else {
    build_weights<<<dim3(CPAD), dim3(256), 0, stream>>>(supports, ent, y_hat, fK, Wt, N);
  }
  gemm_zw<<<dim3(M / BM), dim3(512), 0, stream>>>(z, Wt, out);
}